// Round 7
// baseline (274.933 us; speedup 1.0000x reference)
//
#include <hip/hip_runtime.h>

// Problem constants
#define V_SZ 32000
#define E_SZ 128
#define H_SZ 32
#define L_SZ 64
#define B_SZ 32
#define M_TOT 2048   // L*B rows
#define K2 64        // 2H
#define NVT 125      // V/256 col-slices
#define NMT 32       // M_TOT/64 row-tiles
#define ASUM_LD 128  // padded leading dim of Asum[row][]

typedef __bf16 bf16x8 __attribute__((ext_vector_type(8)));
typedef float f32x4 __attribute__((ext_vector_type(4)));

__device__ __forceinline__ unsigned short f2bf(float f) {
    unsigned int u = __float_as_uint(f);
    u += 0x7FFFu + ((u >> 16) & 1u);   // round-to-nearest-even
    return (unsigned short)(u >> 16);
}

// ---------------------------------------------------------------------------
// Kernel 1: blocks 0..124  -> transpose+convert h2o -> h2oT (256 rows each)
//           blocks 125..156 -> emb-GEMM into LDS + RNN recurrence
// ---------------------------------------------------------------------------
__global__ __launch_bounds__(256) void k_prep_rnn(
    const int* __restrict__ inp, const float* __restrict__ we,
    const float* __restrict__ i2h1, const float* __restrict__ i2h2,
    const float* __restrict__ h2o, const float* __restrict__ bias,
    const float* __restrict__ hinit,
    unsigned short* __restrict__ hcat_u, unsigned short* __restrict__ h2oT_u) {
    const int tid = threadIdx.x;
    const int p = blockIdx.x;
    if (p < 125) {
        const int v = p * 256 + tid;               // [0,32000) exact
        unsigned int* dst = (unsigned int*)(h2oT_u + (size_t)v * K2);
#pragma unroll
        for (int k = 0; k < K2; k += 2) {
            float a = h2o[(size_t)k * V_SZ + v];
            float b = h2o[(size_t)(k + 1) * V_SZ + v];
            dst[k >> 1] = (unsigned int)f2bf(a) | ((unsigned int)f2bf(b) << 16);
        }
        return;
    }
    // ---- emb + RNN block (one direction, 2 batch rows) ----
    const int w2 = p - 125;                        // 0..31
    const int dir = w2 >> 4;
    const int bpair = w2 & 15;
    const float* W = dir ? i2h2 : i2h1;
    __shared__ float Xl[L_SZ * 2 * H_SZ];          // 16 KB: X[t][bb][j]
    {
        const int j = tid & 31, bb = (tid >> 5) & 1, to = tid >> 6;
        const int b = bpair * 2 + bb;
        const float bj = bias[j];
        for (int tt = 0; tt < 16; ++tt) {
            const int t = to * 16 + tt;
            const int idx = inp[t * B_SZ + b];
            const float* er = we + (size_t)idx * E_SZ;
            float acc = bj;
#pragma unroll
            for (int k0 = 0; k0 < E_SZ; k0 += 4) {
                f32x4 e4 = *(const f32x4*)(er + k0);
                acc += e4.x * W[(k0 + 0) * H_SZ + j];
                acc += e4.y * W[(k0 + 1) * H_SZ + j];
                acc += e4.z * W[(k0 + 2) * H_SZ + j];
                acc += e4.w * W[(k0 + 3) * H_SZ + j];
            }
            Xl[(t * 2 + bb) * H_SZ + j] = acc;
        }
    }
    __syncthreads();
    if (tid < 64) {
        const int lane = tid;
        const int bb = lane >> 5;
        const int b = bpair * 2 + bb;
        const int j = lane & 31;
        const int srcbase = lane & 32;
        float wh[H_SZ];
#pragma unroll
        for (int k = 0; k < H_SZ; ++k) wh[k] = W[(E_SZ + k) * H_SZ + j];
        float h = hinit[j];
        for (int step = 0; step < L_SZ; ++step) {
            const int tt = dir ? (L_SZ - 1 - step) : step;
            hcat_u[(tt * B_SZ + b) * K2 + dir * H_SZ + j] = f2bf(h);
            float a0 = Xl[(tt * 2 + bb) * H_SZ + j];
            float a1 = 0.f, a2 = 0.f, a3 = 0.f;
#pragma unroll
            for (int k = 0; k < H_SZ; k += 4) {
                a0 += __shfl(h, srcbase | k, 64) * wh[k];
                a1 += __shfl(h, srcbase | (k + 1), 64) * wh[k + 1];
                a2 += __shfl(h, srcbase | (k + 2), 64) * wh[k + 2];
                a3 += __shfl(h, srcbase | (k + 3), 64) * wh[k + 3];
            }
            float x2 = (a0 + a1) + (a2 + a3);
            float e = __expf(2.f * x2);            // tanh = 1 - 2/(e^{2x}+1)
            h = 1.f - 2.f * __builtin_amdgcn_rcpf(e + 1.f);
        }
    }
}

// ---------------------------------------------------------------------------
// Kernel 2 (pass A, max-free, streamed B): per (row,vtile) sum-exp partials,
// written TRANSPOSED: Asum[row][xcol]. grid (125,32), block 256.
// Streaming keeps ~60 live VGPRs -> 6+ waves/SIMD.
// ---------------------------------------------------------------------------
__global__ __launch_bounds__(256) void k_pass_a(
    const __bf16* __restrict__ hcat, const __bf16* __restrict__ h2oT,
    float* __restrict__ Asum) {
    const int tid = threadIdx.x;
    const int wave = tid >> 6, lane = tid & 63;
    const int wm = wave >> 1, wn = wave & 1;
    const int lg = lane >> 4, lr = lane & 15;
    const int rowbase = blockIdx.y * 64;
    const int colbase = blockIdx.x * 256;
    bf16x8 af[2][2];
#pragma unroll
    for (int m = 0; m < 2; ++m) {
        int row = rowbase + wm * 32 + m * 16 + lr;
#pragma unroll
        for (int kh = 0; kh < 2; ++kh)
            af[m][kh] = *(const bf16x8*)(hcat + row * K2 + kh * 32 + lg * 8);
    }
    float rs[2][4] = {{0.f,0.f,0.f,0.f},{0.f,0.f,0.f,0.f}};
#pragma unroll
    for (int n = 0; n < 8; ++n) {
        const int col = colbase + wn * 128 + n * 16 + lr;
        const __bf16* bp = h2oT + (size_t)col * K2 + lg * 8;
        bf16x8 b0 = *(const bf16x8*)(bp);
        bf16x8 b1 = *(const bf16x8*)(bp + 32);
        f32x4 a0 = (f32x4){0.f,0.f,0.f,0.f}, a1 = (f32x4){0.f,0.f,0.f,0.f};
        a0 = __builtin_amdgcn_mfma_f32_16x16x32_bf16(af[0][0], b0, a0, 0, 0, 0);
        a1 = __builtin_amdgcn_mfma_f32_16x16x32_bf16(af[1][0], b0, a1, 0, 0, 0);
        a0 = __builtin_amdgcn_mfma_f32_16x16x32_bf16(af[0][1], b1, a0, 0, 0, 0);
        a1 = __builtin_amdgcn_mfma_f32_16x16x32_bf16(af[1][1], b1, a1, 0, 0, 0);
#pragma unroll
        for (int r = 0; r < 4; ++r) {
            rs[0][r] += __expf(a0[r]);
            rs[1][r] += __expf(a1[r]);
        }
    }
#pragma unroll
    for (int mask = 1; mask < 16; mask <<= 1)
#pragma unroll
        for (int m = 0; m < 2; ++m)
#pragma unroll
            for (int r = 0; r < 4; ++r)
                rs[m][r] += __shfl_xor(rs[m][r], mask, 64);
    __shared__ float tsum[2][64];
    if (lr == 0) {
#pragma unroll
        for (int m = 0; m < 2; ++m)
#pragma unroll
            for (int r = 0; r < 4; ++r)
                tsum[wn][wm * 32 + m * 16 + lg * 4 + r] = rs[m][r];
    }
    __syncthreads();
    if (tid < 64)
        Asum[(size_t)(rowbase + tid) * ASUM_LD + blockIdx.x] =
            tsum[0][tid] + tsum[1][tid];
}

// ---------------------------------------------------------------------------
// Kernel 3 (pass B, streamed B, fused lse): per block, (a) reduce this
// row-tile's 125 Asum partials -> lse in LDS, (b) recompute logits and
// store logit - lse directly. grid (125,32), block 256.
// ---------------------------------------------------------------------------
__global__ __launch_bounds__(256) void k_pass_b(
    const __bf16* __restrict__ hcat, const __bf16* __restrict__ h2oT,
    const float* __restrict__ Asum, float* __restrict__ out) {
    const int tid = threadIdx.x;
    const int wave = tid >> 6, lane = tid & 63;
    const int wm = wave >> 1, wn = wave & 1;
    const int lg = lane >> 4, lr = lane & 15;
    const int rowbase = blockIdx.y * 64;
    const int colbase = blockIdx.x * 256;

    // ---- (a) lse for the 64 rows of this tile ----
    __shared__ float part[64][4];
    __shared__ float lse_s[64];
    {
        const int r = tid >> 2, q = tid & 3;
        const int i0 = q * 32;
        const int i1 = (q == 3) ? NVT : (i0 + 32);
        const float* ap = Asum + (size_t)(rowbase + r) * ASUM_LD;
        float s = 0.f;
        for (int i = i0; i < i1; ++i) s += ap[i];
        part[r][q] = s;
    }
    __syncthreads();
    if (tid < 64)
        lse_s[tid] = logf(part[tid][0] + part[tid][1] + part[tid][2] + part[tid][3]);
    __syncthreads();

    // ---- (b) recompute + store ----
    bf16x8 af[2][2];
#pragma unroll
    for (int m = 0; m < 2; ++m) {
        int row = rowbase + wm * 32 + m * 16 + lr;
#pragma unroll
        for (int kh = 0; kh < 2; ++kh)
            af[m][kh] = *(const bf16x8*)(hcat + row * K2 + kh * 32 + lg * 8);
    }
    float lsev[2][4];
#pragma unroll
    for (int m = 0; m < 2; ++m)
#pragma unroll
        for (int r = 0; r < 4; ++r)
            lsev[m][r] = lse_s[wm * 32 + m * 16 + lg * 4 + r];
#pragma unroll
    for (int n = 0; n < 8; ++n) {
        const int col = colbase + wn * 128 + n * 16 + lr;
        const __bf16* bp = h2oT + (size_t)col * K2 + lg * 8;
        bf16x8 b0 = *(const bf16x8*)(bp);
        bf16x8 b1 = *(const bf16x8*)(bp + 32);
        f32x4 a0 = (f32x4){0.f,0.f,0.f,0.f}, a1 = (f32x4){0.f,0.f,0.f,0.f};
        a0 = __builtin_amdgcn_mfma_f32_16x16x32_bf16(af[0][0], b0, a0, 0, 0, 0);
        a1 = __builtin_amdgcn_mfma_f32_16x16x32_bf16(af[1][0], b0, a1, 0, 0, 0);
        a0 = __builtin_amdgcn_mfma_f32_16x16x32_bf16(af[0][1], b1, a0, 0, 0, 0);
        a1 = __builtin_amdgcn_mfma_f32_16x16x32_bf16(af[1][1], b1, a1, 0, 0, 0);
#pragma unroll
        for (int r = 0; r < 4; ++r) {
            const int row0 = rowbase + wm * 32 + lg * 4 + r;
            out[(size_t)(row0)      * V_SZ + colbase + wn * 128 + n * 16 + lr] =
                a0[r] - lsev[0][r];
            out[(size_t)(row0 + 16) * V_SZ + colbase + wn * 128 + n * 16 + lr] =
                a1[r] - lsev[1][r];
        }
    }
}

// ---------------------------------------------------------------------------
extern "C" void kernel_launch(void* const* d_in, const int* in_sizes, int n_in,
                              void* d_out, int out_size, void* d_ws, size_t ws_size,
                              hipStream_t stream) {
    (void)in_sizes; (void)n_in; (void)out_size; (void)ws_size;
    const int*   inp   = (const int*)d_in[0];
    const float* we    = (const float*)d_in[1];
    const float* i2h1  = (const float*)d_in[2];
    const float* i2h2  = (const float*)d_in[3];
    const float* h2o   = (const float*)d_in[4];
    const float* bias  = (const float*)d_in[5];
    const float* hinit = (const float*)d_in[6];
    float* out = (float*)d_out;
    char* ws = (char*)d_ws;
    unsigned short* hcat_u = (unsigned short*)(ws);           // 262144 B
    unsigned short* h2oT_u = (unsigned short*)(ws + 262144);  // 4096000 B
    float*          Asum   = (float*)(ws + 4358144);          // 1048576 B

    k_prep_rnn<<<157, 256, 0, stream>>>(inp, we, i2h1, i2h2, h2o, bias, hinit,
                                        hcat_u, h2oT_u);
    k_pass_a<<<dim3(NVT, NMT), 256, 0, stream>>>(
        (const __bf16*)hcat_u, (const __bf16*)h2oT_u, Asum);
    k_pass_b<<<dim3(NVT, NMT), 256, 0, stream>>>(
        (const __bf16*)hcat_u, (const __bf16*)h2oT_u, Asum, out);
}

// Round 8
// 186.038 us; speedup vs baseline: 1.4778x; 1.4778x over previous
//
#include <hip/hip_runtime.h>

// Problem constants
#define V_SZ 32000
#define E_SZ 128
#define H_SZ 32
#define L_SZ 64
#define B_SZ 32
#define M_TOT 2048   // L*B rows
#define K2 64        // 2H
#define NVT 125      // V/256 col-slices
#define NMT 32       // M_TOT/64 row-tiles

typedef __bf16 bf16x8 __attribute__((ext_vector_type(8)));
typedef float f32x4 __attribute__((ext_vector_type(4)));

__device__ __forceinline__ unsigned short f2bf(float f) {
    unsigned int u = __float_as_uint(f);
    u += 0x7FFFu + ((u >> 16) & 1u);   // round-to-nearest-even
    return (unsigned short)(u >> 16);
}

// ---------------------------------------------------------------------------
// R6-proven device helpers: ALL B fragments resident in registers before any
// MFMA (16 outstanding 16B loads = the MLP that R7's streaming destroyed).
// C layout: row = wm*32 + m*16 + lg*4 + r, col = wn*128 + n*16 + lr.
// ---------------------------------------------------------------------------
__device__ __forceinline__ void load_bfrag(
    const __bf16* __restrict__ h2oT, int xcol, int wn, int lg, int lr,
    bf16x8 bfr[8][2]) {
    const int colbase = xcol * 256;
#pragma unroll
    for (int n = 0; n < 8; ++n) {
        int col = colbase + wn * 128 + n * 16 + lr;
        const __bf16* bp = h2oT + (size_t)col * K2 + lg * 8;
        bfr[n][0] = *(const bf16x8*)(bp);
        bfr[n][1] = *(const bf16x8*)(bp + 32);
    }
}

__device__ __forceinline__ void tile_gemm(
    const __bf16* __restrict__ hcat, int rowbase, int wm, int lg, int lr,
    const bf16x8 bfr[8][2], f32x4 acc[2][8]) {
    bf16x8 af[2][2];
#pragma unroll
    for (int m = 0; m < 2; ++m) {
        int row = rowbase + wm * 32 + m * 16 + lr;
#pragma unroll
        for (int kh = 0; kh < 2; ++kh)
            af[m][kh] = *(const bf16x8*)(hcat + row * K2 + kh * 32 + lg * 8);
    }
#pragma unroll
    for (int m = 0; m < 2; ++m)
#pragma unroll
        for (int n = 0; n < 8; ++n) acc[m][n] = (f32x4){0.f, 0.f, 0.f, 0.f};
#pragma unroll
    for (int n = 0; n < 8; ++n)
#pragma unroll
        for (int m = 0; m < 2; ++m) {
            acc[m][n] = __builtin_amdgcn_mfma_f32_16x16x32_bf16(af[m][0], bfr[n][0], acc[m][n], 0, 0, 0);
            acc[m][n] = __builtin_amdgcn_mfma_f32_16x16x32_bf16(af[m][1], bfr[n][1], acc[m][n], 0, 0, 0);
        }
}

// ---------------------------------------------------------------------------
// Kernel 1: blocks 0..124  -> transpose+convert h2o -> h2oT (256 rows each)
//           blocks 125..156 -> emb-GEMM into LDS + RNN recurrence
// (unchanged, R6/R7-proven)
// ---------------------------------------------------------------------------
__global__ __launch_bounds__(256) void k_prep_rnn(
    const int* __restrict__ inp, const float* __restrict__ we,
    const float* __restrict__ i2h1, const float* __restrict__ i2h2,
    const float* __restrict__ h2o, const float* __restrict__ bias,
    const float* __restrict__ hinit,
    unsigned short* __restrict__ hcat_u, unsigned short* __restrict__ h2oT_u) {
    const int tid = threadIdx.x;
    const int p = blockIdx.x;
    if (p < 125) {
        const int v = p * 256 + tid;               // [0,32000) exact
        unsigned int* dst = (unsigned int*)(h2oT_u + (size_t)v * K2);
#pragma unroll
        for (int k = 0; k < K2; k += 2) {
            float a = h2o[(size_t)k * V_SZ + v];
            float b = h2o[(size_t)(k + 1) * V_SZ + v];
            dst[k >> 1] = (unsigned int)f2bf(a) | ((unsigned int)f2bf(b) << 16);
        }
        return;
    }
    // ---- emb + RNN block (one direction, 2 batch rows) ----
    const int w2 = p - 125;                        // 0..31
    const int dir = w2 >> 4;
    const int bpair = w2 & 15;
    const float* W = dir ? i2h2 : i2h1;
    __shared__ float Xl[L_SZ * 2 * H_SZ];          // 16 KB: X[t][bb][j]
    {
        const int j = tid & 31, bb = (tid >> 5) & 1, to = tid >> 6;
        const int b = bpair * 2 + bb;
        const float bj = bias[j];
        for (int tt = 0; tt < 16; ++tt) {
            const int t = to * 16 + tt;
            const int idx = inp[t * B_SZ + b];
            const float* er = we + (size_t)idx * E_SZ;
            float acc = bj;
#pragma unroll
            for (int k0 = 0; k0 < E_SZ; k0 += 4) {
                f32x4 e4 = *(const f32x4*)(er + k0);
                acc += e4.x * W[(k0 + 0) * H_SZ + j];
                acc += e4.y * W[(k0 + 1) * H_SZ + j];
                acc += e4.z * W[(k0 + 2) * H_SZ + j];
                acc += e4.w * W[(k0 + 3) * H_SZ + j];
            }
            Xl[(t * 2 + bb) * H_SZ + j] = acc;
        }
    }
    __syncthreads();
    if (tid < 64) {
        const int lane = tid;
        const int bb = lane >> 5;
        const int b = bpair * 2 + bb;
        const int j = lane & 31;
        const int srcbase = lane & 32;
        float wh[H_SZ];
#pragma unroll
        for (int k = 0; k < H_SZ; ++k) wh[k] = W[(E_SZ + k) * H_SZ + j];
        float h = hinit[j];
        for (int step = 0; step < L_SZ; ++step) {
            const int tt = dir ? (L_SZ - 1 - step) : step;
            hcat_u[(tt * B_SZ + b) * K2 + dir * H_SZ + j] = f2bf(h);
            float a0 = Xl[(tt * 2 + bb) * H_SZ + j];
            float a1 = 0.f, a2 = 0.f, a3 = 0.f;
#pragma unroll
            for (int k = 0; k < H_SZ; k += 4) {
                a0 += __shfl(h, srcbase | k, 64) * wh[k];
                a1 += __shfl(h, srcbase | (k + 1), 64) * wh[k + 1];
                a2 += __shfl(h, srcbase | (k + 2), 64) * wh[k + 2];
                a3 += __shfl(h, srcbase | (k + 3), 64) * wh[k + 3];
            }
            float x2 = (a0 + a1) + (a2 + a3);
            float e = __expf(2.f * x2);            // tanh = 1 - 2/(e^{2x}+1)
            h = 1.f - 2.f * __builtin_amdgcn_rcpf(e + 1.f);
        }
    }
}

// ---------------------------------------------------------------------------
// Kernel 2 (pass A, max-free, B-resident): per (row,vtile) sum-exp partials.
// grid (125,32), block 256. (R6-proven, unchanged)
// ---------------------------------------------------------------------------
__global__ __launch_bounds__(256) void k_pass_a(
    const __bf16* __restrict__ hcat, const __bf16* __restrict__ h2oT,
    float* __restrict__ Asum) {
    const int tid = threadIdx.x;
    const int wave = tid >> 6, lane = tid & 63;
    const int wm = wave >> 1, wn = wave & 1;
    const int lg = lane >> 4, lr = lane & 15;
    const int rowbase = blockIdx.y * 64;
    bf16x8 bfr[8][2];
    load_bfrag(h2oT, blockIdx.x, wn, lg, lr, bfr);
    f32x4 acc[2][8];
    tile_gemm(hcat, rowbase, wm, lg, lr, bfr, acc);
    float rs[2][4];
#pragma unroll
    for (int m = 0; m < 2; ++m)
#pragma unroll
        for (int r = 0; r < 4; ++r) {
            float s = 0.f;
#pragma unroll
            for (int n = 0; n < 8; ++n) s += __expf(acc[m][n][r]);
            rs[m][r] = s;
        }
#pragma unroll
    for (int mask = 1; mask < 16; mask <<= 1)
#pragma unroll
        for (int m = 0; m < 2; ++m)
#pragma unroll
            for (int r = 0; r < 4; ++r)
                rs[m][r] += __shfl_xor(rs[m][r], mask, 64);
    __shared__ float tsum[2][64];
    if (lr == 0) {
#pragma unroll
        for (int m = 0; m < 2; ++m)
#pragma unroll
            for (int r = 0; r < 4; ++r)
                tsum[wn][wm * 32 + m * 16 + lg * 4 + r] = rs[m][r];
    }
    __syncthreads();
    if (tid < 64)
        Asum[blockIdx.x * M_TOT + rowbase + tid] = tsum[0][tid] + tsum[1][tid];
}

// ---------------------------------------------------------------------------
// Kernel 3: reduce partials over 125 v-tiles -> lse[row] = log(sum)
// (R6-proven, unchanged)
// ---------------------------------------------------------------------------
__global__ __launch_bounds__(256) void k_lse(
    const float* __restrict__ Asum, float* __restrict__ lse) {
    const int row = blockIdx.x * 256 + threadIdx.x;
    float s = 0.f;
    for (int i = 0; i < NVT; ++i) s += Asum[i * M_TOT + row];
    lse[row] = logf(s);
}

// ---------------------------------------------------------------------------
// Kernel 4 (pass B): B-resident GEMM (R6) + two-chunk LDS repack with
// coalesced f32x4 full-line stores (R3-proven epilogue). Kills the RMW
// write-amplification seen in R7 (FETCH 69 MB -> ~15 MB).
// ---------------------------------------------------------------------------
__global__ __launch_bounds__(256) void k_pass_b(
    const __bf16* __restrict__ hcat, const __bf16* __restrict__ h2oT,
    const float* __restrict__ lse, float* __restrict__ out) {
    const int tid = threadIdx.x;
    const int wave = tid >> 6, lane = tid & 63;
    const int wm = wave >> 1, wn = wave & 1;
    const int lg = lane >> 4, lr = lane & 15;
    const int rowbase = blockIdx.y * 64;
    const int colbase = blockIdx.x * 256;
    bf16x8 bfr[8][2];
    load_bfrag(h2oT, blockIdx.x, wn, lg, lr, bfr);
    f32x4 acc[2][8];
    tile_gemm(hcat, rowbase, wm, lg, lr, bfr, acc);
    float lsev[2][4];
#pragma unroll
    for (int m = 0; m < 2; ++m)
#pragma unroll
        for (int r = 0; r < 4; ++r)
            lsev[m][r] = lse[rowbase + wm * 32 + m * 16 + lg * 4 + r];

    __shared__ float cbuf[32 * 260];   // 33.3 KB; pad 260 breaks conflicts
#pragma unroll
    for (int c = 0; c < 2; ++c) {
        if (c) __syncthreads();        // WAR guard on cbuf reuse
#pragma unroll
        for (int n = 0; n < 8; ++n)
#pragma unroll
            for (int r = 0; r < 4; ++r)
                cbuf[(wm * 16 + lg * 4 + r) * 260 + wn * 128 + n * 16 + lr] =
                    acc[c][n][r] - lsev[c][r];
        __syncthreads();
#pragma unroll
        for (int it = 0; it < 8; ++it) {
            int idx4 = it * 256 + tid;     // float4 index in 32x256 chunk
            int lrow = idx4 >> 6;          // 64 float4 per row
            int col = (idx4 & 63) << 2;
            int grow = rowbase + (lrow >> 4) * 32 + c * 16 + (lrow & 15);
            f32x4 v = *(const f32x4*)&cbuf[lrow * 260 + col];
            *(f32x4*)(out + (size_t)grow * V_SZ + colbase + col) = v;
        }
    }
}

// ---------------------------------------------------------------------------
extern "C" void kernel_launch(void* const* d_in, const int* in_sizes, int n_in,
                              void* d_out, int out_size, void* d_ws, size_t ws_size,
                              hipStream_t stream) {
    (void)in_sizes; (void)n_in; (void)out_size; (void)ws_size;
    const int*   inp   = (const int*)d_in[0];
    const float* we    = (const float*)d_in[1];
    const float* i2h1  = (const float*)d_in[2];
    const float* i2h2  = (const float*)d_in[3];
    const float* h2o   = (const float*)d_in[4];
    const float* bias  = (const float*)d_in[5];
    const float* hinit = (const float*)d_in[6];
    float* out = (float*)d_out;
    char* ws = (char*)d_ws;
    unsigned short* hcat_u = (unsigned short*)(ws);           // 262144 B
    unsigned short* h2oT_u = (unsigned short*)(ws + 262144);  // 4096000 B
    float*          Asum   = (float*)(ws + 4358144);          // 1024000 B
    float*          lse    = (float*)(ws + 5382144);          // 8192 B

    k_prep_rnn<<<157, 256, 0, stream>>>(inp, we, i2h1, i2h2, h2o, bias, hinit,
                                        hcat_u, h2oT_u);
    k_pass_a<<<dim3(NVT, NMT), 256, 0, stream>>>(
        (const __bf16*)hcat_u, (const __bf16*)h2oT_u, Asum);
    k_lse<<<8, 256, 0, stream>>>(Asum, lse);
    k_pass_b<<<dim3(NVT, NMT), 256, 0, stream>>>(
        (const __bf16*)hcat_u, (const __bf16*)h2oT_u, lse, out);
}